// Round 5
// baseline (573.156 us; speedup 1.0000x reference)
//
#include <hip/hip_runtime.h>

// Problem constants
#define D_  1024
#define S_  2048
#define B_  4
#define H_  16
#define HD_ 64
#define BS_ (B_*S_)   // 8192 rows

// GEMM tiling (m97 structure)
#define BM 128
#define BN 128
#define BK 32
#define NT (D_ / BK)   // 32 K-steps

typedef __attribute__((ext_vector_type(8))) short short8;   // 8 bf16 = 4 VGPRs
typedef __attribute__((ext_vector_type(4))) float floatx4;  // MFMA C/D
typedef __attribute__((ext_vector_type(4))) unsigned int uint4v;

typedef __attribute__((address_space(3))) unsigned int lds_uint;
typedef const __attribute__((address_space(1))) unsigned int glob_uint;

// Workspace layout (byte offsets), 72 MB total.
#define WS_XB ((size_t)0)            // 16 MB bf16 x
#define WS_WQ ((size_t)16 << 20)     // 2 MB bf16 Wq
#define WS_WK ((size_t)18 << 20)
#define WS_WV ((size_t)20 << 20)
#define WS_WO ((size_t)22 << 20)
#define WS_Q  ((size_t)24 << 20)     // 16 MB bf16 Q [b,h,s,hd]
#define WS_KK ((size_t)40 << 20)     // 16 MB bf16 K [b,h,s,hd]
#define WS_VT ((size_t)56 << 20)     // 16 MB bf16 V^T [b,h,hd,s]
#define WS_Y  WS_Q                   // y (fp32, 32 MB) overlays Q+K after attn

static __device__ __forceinline__ unsigned short f2bf(float f) {
  unsigned u = __builtin_bit_cast(unsigned, f);
  unsigned r = (u + 0x7fffu + ((u >> 16) & 1u)) >> 16;  // RNE
  return (unsigned short)r;
}

static __device__ __forceinline__ unsigned cvtpk_bf16(float lo, float hi) {
  unsigned r;
  asm("v_cvt_pk_bf16_f32 %0, %1, %2" : "=v"(r) : "v"(lo), "v"(hi));
  return r;
}

#define PSWAP(a, b) asm("v_permlane32_swap_b32 %0, %1" : "+v"(a), "+v"(b))

// ---------------------------------------------------------------------------
// Kernel 0: fp32 -> bf16 convert (RNE), 4 elements per thread.
// ---------------------------------------------------------------------------
__global__ __launch_bounds__(256) void cvt_f32_bf16(
    const float* __restrict__ src, unsigned short* __restrict__ dst, int n4)
{
  int i = blockIdx.x * 256 + threadIdx.x;
  if (i < n4) {
    float4 v = ((const float4*)src)[i];
    ushort4 o;
    o.x = f2bf(v.x); o.y = f2bf(v.y); o.z = f2bf(v.z); o.w = f2bf(v.w);
    ((ushort4*)dst)[i] = o;
  }
}

// ---------------------------------------------------------------------------
// Tiled GEMM mainloop (shared by gemm_qkv / gemm_out). m97 structure.
// ---------------------------------------------------------------------------
#define GEMM_MAINLOOP(Aptr, Bptr)                                              \
  __shared__ unsigned short lds[2][2][BM * BK];                                \
  const int tid  = threadIdx.x;                                                \
  const int wv   = tid >> 6;                                                   \
  const int lane = tid & 63;                                                   \
  const int c    = lane & 15;                                                  \
  const int quad = lane >> 4;                                                  \
  const int m0   = blockIdx.x * BM;                                            \
  const int n0   = blockIdx.y * BN;                                            \
  const int srow = lane >> 2;                                                  \
  const int scol = (lane & 3) * 8;                                             \
  const unsigned short* gA = (Aptr) + (size_t)(m0 + wv * 16 + srow) * D_ + scol;\
  const unsigned short* gB = (Bptr) + (size_t)(n0 + wv * 16 + srow) * D_ + scol;\
  const int lbase = (wv * 16) * BK;                                            \
  const int wr = (wv >> 1) * 64;                                               \
  const int wc = (wv & 1) * 64;                                                \
  floatx4 acc[4][4];                                                           \
  _Pragma("unroll")                                                            \
  for (int mi = 0; mi < 4; ++mi)                                               \
    _Pragma("unroll")                                                          \
    for (int ni = 0; ni < 4; ++ni) acc[mi][ni] = (floatx4){0.f,0.f,0.f,0.f};   \
  auto stage = [&](int buf, int t) {                                           \
    const size_t koff = (size_t)t * BK;                                        \
    _Pragma("unroll")                                                          \
    for (int j = 0; j < 2; ++j) {                                              \
      __builtin_amdgcn_global_load_lds(                                        \
          (glob_uint*)(gA + (size_t)j * 64 * D_ + koff),                       \
          (lds_uint*)&lds[buf][0][j * 64 * BK + lbase], 16, 0, 0);             \
      __builtin_amdgcn_global_load_lds(                                        \
          (glob_uint*)(gB + (size_t)j * 64 * D_ + koff),                       \
          (lds_uint*)&lds[buf][1][j * 64 * BK + lbase], 16, 0, 0);             \
    }                                                                          \
  };                                                                           \
  stage(0, 0);                                                                 \
  __syncthreads();                                                             \
  int cur = 0;                                                                 \
  for (int t = 0; t < NT; ++t) {                                               \
    if (t + 1 < NT) stage(cur ^ 1, t + 1);                                     \
    const unsigned short* LA = &lds[cur][0][0];                                \
    const unsigned short* LB = &lds[cur][1][0];                                \
    short8 af[4], bf[4];                                                       \
    _Pragma("unroll")                                                          \
    for (int i = 0; i < 4; ++i) {                                              \
      af[i] = *(const short8*)&LA[(wr + i * 16 + c) * BK + quad * 8];          \
      bf[i] = *(const short8*)&LB[(wc + i * 16 + c) * BK + quad * 8];          \
    }                                                                          \
    _Pragma("unroll")                                                          \
    for (int mi = 0; mi < 4; ++mi)                                             \
      _Pragma("unroll")                                                        \
      for (int ni = 0; ni < 4; ++ni)                                           \
        acc[mi][ni] = __builtin_amdgcn_mfma_f32_16x16x32_bf16(                 \
            af[mi], bf[ni], acc[mi][ni], 0, 0, 0);                             \
    __syncthreads();                                                           \
    cur ^= 1;                                                                  \
  }

// ---------------------------------------------------------------------------
// Kernel 1: QKV projection (tiled). mode = blockIdx.z:
//   0 -> Q [b,h,s,hd]; 1 -> K [b,h,s,hd]; 2 -> V^T [b,h,hd,s].
// ---------------------------------------------------------------------------
__global__ __launch_bounds__(256) void gemm_qkv(
    const unsigned short* __restrict__ X,
    const unsigned short* __restrict__ Wq, const float* __restrict__ bq,
    const unsigned short* __restrict__ Wk, const float* __restrict__ bk,
    const unsigned short* __restrict__ Wv, const float* __restrict__ bv,
    unsigned short* __restrict__ Qo, unsigned short* __restrict__ Ko,
    unsigned short* __restrict__ Vo)
{
  const int mode = blockIdx.z;
  const unsigned short* W = (mode == 0) ? Wq : ((mode == 1) ? Wk : Wv);
  const float* bias       = (mode == 0) ? bq : ((mode == 1) ? bk : bv);
  unsigned short* dst     = (mode == 0) ? Qo : ((mode == 1) ? Ko : Vo);

  GEMM_MAINLOOP(X, W)

  const int b = m0 >> 11;
  #pragma unroll
  for (int mi = 0; mi < 4; ++mi) {
    const int sb = (m0 & (S_ - 1)) + wr + mi * 16 + quad * 4;
    #pragma unroll
    for (int ni = 0; ni < 4; ++ni) {
      const int n   = n0 + wc + ni * 16 + c;
      const float bv_ = bias[n];
      const int h  = n >> 6;
      const int hd = n & 63;
      if (mode < 2) {
        size_t base = ((size_t)((b * H_ + h) * S_ + sb)) * HD_ + hd;
        #pragma unroll
        for (int r = 0; r < 4; ++r)
          dst[base + (size_t)r * HD_] = f2bf(acc[mi][ni][r] + bv_);
      } else {
        size_t base = ((size_t)((b * H_ + h) * HD_ + hd)) * S_ + sb;
        ushort4 o;
        o.x = f2bf(acc[mi][ni][0] + bv_);
        o.y = f2bf(acc[mi][ni][1] + bv_);
        o.z = f2bf(acc[mi][ni][2] + bv_);
        o.w = f2bf(acc[mi][ni][3] + bv_);
        *(ushort4*)&dst[base] = o;
      }
    }
  }
}

// ---------------------------------------------------------------------------
// Kernel 2 (v7): flash attention with explicit register prefetch.
// Same math/mapping as v6 (verified). Changes:
//  - amdgpu_waves_per_eu(4,4): max=4 stops the occupancy-greedy scheduler
//    from squeezing to 64 VGPRs (v6: 60 VGPR, all pipes idle). Budget = 128.
//  - flattened 64-chunk loop (kc0 = idx*32). Per chunk:
//      1) issue all 8 V loads (latency covered by QK^T + exp)
//      2) QK^T from K frags prefetched LAST chunk
//      3) prefetch next chunk's K frags + mask into named registers
//         (latency covered by exp + PV)
//      4) exp/pack  5) PV  6) rotate prefetch regs
// P-frag slot->k map: k = kc0 + (quad>>1)*16 + (quad&1)*4 + (e>>2)*8 + (e&3).
// V frag: two 8B loads at +0 / +8 elements.
// ---------------------------------------------------------------------------
__global__ __launch_bounds__(256)
__attribute__((amdgpu_waves_per_eu(4, 4)))
void attn_kernel(
    const unsigned short* __restrict__ Q, const unsigned short* __restrict__ K,
    const unsigned short* __restrict__ Vt, const int* __restrict__ mask,
    unsigned short* __restrict__ ctx)
{
  const int wv   = threadIdx.x >> 6;
  const int lane = threadIdx.x & 63;
  const int c    = lane & 15;
  const int quad = lane >> 4;

  const int id = blockIdx.x;
  const int bh = (id & 7) + 8 * (id >> 7);   // bh%8 == id%8 (XCD co-location)
  const int qt = (id >> 3) & 15;
  const int b  = bh >> 4;
  const int h  = bh & 15;
  const int q0 = qt * 128 + wv * 32;         // 32 q-rows per wave

  const unsigned short* Qb = Q  + (size_t)bh * S_ * HD_;
  const unsigned short* Kb = K  + (size_t)bh * S_ * HD_;
  const unsigned short* Vb = Vt + (size_t)bh * HD_ * S_;
  const int* mrow = mask + b * S_;

  // Q as B-fragments (B-row j = q = lane&15)
  short8 bQ[2][2];
  #pragma unroll
  for (int s = 0; s < 2; ++s) {
    const unsigned short* qrow = Qb + (size_t)(q0 + s * 16 + c) * HD_;
    bQ[s][0] = *(const short8*)(qrow + quad * 8);
    bQ[s][1] = *(const short8*)(qrow + 32 + quad * 8);
  }

  floatx4 acc[2][4];
  #pragma unroll
  for (int s = 0; s < 2; ++s)
    #pragma unroll
    for (int d = 0; d < 4; ++d) acc[s][d] = (floatx4){0.f, 0.f, 0.f, 0.f};
  float lsum[2] = {0.f, 0.f};

  const int voff = (quad & 1) * 4 + (quad >> 1) * 16;

  auto loadK = [&](int kc0, short8 (&kfo)[2][2], int4 (&mko)[2]) {
    #pragma unroll
    for (int ct2 = 0; ct2 < 2; ++ct2) {
      const unsigned short* krow = Kb + (size_t)(kc0 + ct2 * 16 + c) * HD_;
      kfo[ct2][0] = *(const short8*)(krow + quad * 8);
      kfo[ct2][1] = *(const short8*)(krow + 32 + quad * 8);
      mko[ct2] = *(const int4*)(mrow + kc0 + ct2 * 16 + quad * 4);
    }
  };

  short8 kf[2][2];
  int4   mk[2];
  loadK(0, kf, mk);

  for (int idx = 0; idx < 64; ++idx) {
    const int kc0 = idx * 32;

    // ---- 1) issue V loads for the CURRENT chunk (independent of compute) --
    uint2 vl[4], vh[4];
    #pragma unroll
    for (int dt = 0; dt < 4; ++dt) {
      const unsigned short* vrow = Vb + (size_t)(dt * 16 + c) * S_ + kc0 + voff;
      vl[dt] = *(const uint2*)(vrow);        // k offsets +0..+3
      vh[dt] = *(const uint2*)(vrow + 8);    // k offsets +8..+11
    }

    // ---- 2) QK^T (swapped) from prefetched K frags ----
    floatx4 Cm[2][2];
    #pragma unroll
    for (int ct2 = 0; ct2 < 2; ++ct2) {
      floatx4 z0 = {0.f,0.f,0.f,0.f}, z1 = {0.f,0.f,0.f,0.f};
      z0 = __builtin_amdgcn_mfma_f32_16x16x32_bf16(kf[ct2][0], bQ[0][0], z0, 0, 0, 0);
      z1 = __builtin_amdgcn_mfma_f32_16x16x32_bf16(kf[ct2][0], bQ[1][0], z1, 0, 0, 0);
      z0 = __builtin_amdgcn_mfma_f32_16x16x32_bf16(kf[ct2][1], bQ[0][1], z0, 0, 0, 0);
      z1 = __builtin_amdgcn_mfma_f32_16x16x32_bf16(kf[ct2][1], bQ[1][1], z1, 0, 0, 0);
      Cm[0][ct2] = z0;
      Cm[1][ct2] = z1;
    }

    // ---- 3) prefetch NEXT chunk's K + mask into registers ----
    short8 kn[2][2];
    int4   mn[2];
    loadK((idx < 63) ? kc0 + 32 : 0, kn, mn);

    // ---- 4) mask + exp (static max) + lane-local l + pack ----
    unsigned w[2][2][2];
    #pragma unroll
    for (int ct2 = 0; ct2 < 2; ++ct2) {
      const float mb0 = (mk[ct2].x == 0) ? -1e30f : 0.f;
      const float mb1 = (mk[ct2].y == 0) ? -1e30f : 0.f;
      const float mb2 = (mk[ct2].z == 0) ? -1e30f : 0.f;
      const float mb3 = (mk[ct2].w == 0) ? -1e30f : 0.f;
      #pragma unroll
      for (int s = 0; s < 2; ++s) {
        float p0 = __expf(fmaf(Cm[s][ct2][0], 0.125f, mb0));
        float p1 = __expf(fmaf(Cm[s][ct2][1], 0.125f, mb1));
        float p2 = __expf(fmaf(Cm[s][ct2][2], 0.125f, mb2));
        float p3 = __expf(fmaf(Cm[s][ct2][3], 0.125f, mb3));
        lsum[s] += (p0 + p1) + (p2 + p3);
        w[s][ct2][0] = cvtpk_bf16(p0, p1);
        w[s][ct2][1] = cvtpk_bf16(p2, p3);
      }
    }

    // ---- 5) PV: P B-frags in-register; V A-frags shared by subtiles ----
    short8 pf[2];
    #pragma unroll
    for (int s = 0; s < 2; ++s) {
      unsigned a0 = w[s][0][0], a1 = w[s][0][1];
      unsigned b0 = w[s][1][0], b1 = w[s][1][1];
      PSWAP(a0, b0);
      PSWAP(a1, b1);
      uint4v pw = {a0, a1, b0, b1};
      pf[s] = __builtin_bit_cast(short8, pw);
    }
    #pragma unroll
    for (int dt = 0; dt < 4; ++dt) {
      uint4v vw = {vl[dt].x, vl[dt].y, vh[dt].x, vh[dt].y};
      short8 vf = __builtin_bit_cast(short8, vw);
      acc[0][dt] = __builtin_amdgcn_mfma_f32_16x16x32_bf16(vf, pf[0], acc[0][dt], 0, 0, 0);
      acc[1][dt] = __builtin_amdgcn_mfma_f32_16x16x32_bf16(vf, pf[1], acc[1][dt], 0, 0, 0);
    }

    // ---- 6) rotate prefetch registers ----
    #pragma unroll
    for (int ct2 = 0; ct2 < 2; ++ct2) {
      kf[ct2][0] = kn[ct2][0];
      kf[ct2][1] = kn[ct2][1];
      mk[ct2]    = mn[ct2];
    }
  }

  // ---- epilogue: cross-quad l reduce (only shuffles in the kernel) ----
  #pragma unroll
  for (int s = 0; s < 2; ++s) {
    float l = lsum[s];
    l += __shfl_xor(l, 16);
    l += __shfl_xor(l, 32);
    const float inv = 1.f / l;
    #pragma unroll
    for (int dt = 0; dt < 4; ++dt) {
      ushort4 o;
      o.x = f2bf(acc[s][dt][0] * inv);
      o.y = f2bf(acc[s][dt][1] * inv);
      o.z = f2bf(acc[s][dt][2] * inv);
      o.w = f2bf(acc[s][dt][3] * inv);
      *(ushort4*)&ctx[((size_t)(b * S_ + q0 + s * 16 + c)) * D_ +
                      h * HD_ + dt * 16 + quad * 4] = o;
    }
  }
}

// ---------------------------------------------------------------------------
// Kernel 3: out-proj + residual (tiled). y[m,n] = ctx@Wo.T + bo + x. y fp32.
// ---------------------------------------------------------------------------
__global__ __launch_bounds__(256) void gemm_out(
    const unsigned short* __restrict__ CTX, const unsigned short* __restrict__ W,
    const float* __restrict__ bo, const float* __restrict__ X,
    float* __restrict__ Y)
{
  GEMM_MAINLOOP(CTX, W)

  #pragma unroll
  for (int mi = 0; mi < 4; ++mi) {
    const int m = m0 + wr + mi * 16 + quad * 4;
    #pragma unroll
    for (int ni = 0; ni < 4; ++ni) {
      const int n = n0 + wc + ni * 16 + c;
      const float bias = bo[n];
      #pragma unroll
      for (int r = 0; r < 4; ++r)
        Y[(size_t)(m + r) * D_ + n] =
            acc[mi][ni][r] + bias + X[(size_t)(m + r) * D_ + n];
    }
  }
}

// ---------------------------------------------------------------------------
// Kernel 4: LayerNorm over last dim (1024). y fp32 in; OUTPUT FP32.
// ---------------------------------------------------------------------------
__global__ __launch_bounds__(256) void ln_kernel(
    const float* __restrict__ Y, const float* __restrict__ gamma,
    const float* __restrict__ beta, float* __restrict__ out)
{
  __shared__ float red[2][4];
  const int row  = blockIdx.x;
  const int tid  = threadIdx.x;
  const int wv   = tid >> 6;
  const int lane = tid & 63;
  const float* y = Y + (size_t)row * D_;

  float v[4];
  float sum = 0.f, sumsq = 0.f;
  #pragma unroll
  for (int i = 0; i < 4; ++i) {
    v[i] = y[tid + i * 256];
    sum += v[i];
    sumsq += v[i] * v[i];
  }
  #pragma unroll
  for (int off = 32; off > 0; off >>= 1) {
    sum   += __shfl_down(sum, off, 64);
    sumsq += __shfl_down(sumsq, off, 64);
  }
  if (lane == 0) { red[0][wv] = sum; red[1][wv] = sumsq; }
  __syncthreads();
  sum   = red[0][0] + red[0][1] + red[0][2] + red[0][3];
  sumsq = red[1][0] + red[1][1] + red[1][2] + red[1][3];

  const float mu   = sum * (1.f / D_);
  const float var  = sumsq * (1.f / D_) - mu * mu;
  const float rstd = rsqrtf(var + 1e-5f);

  #pragma unroll
  for (int i = 0; i < 4; ++i) {
    const int col = tid + i * 256;
    out[(size_t)row * D_ + col] = (v[i] - mu) * rstd * gamma[col] + beta[col];
  }
}

// ---------------------------------------------------------------------------
extern "C" void kernel_launch(void* const* d_in, const int* in_sizes, int n_in,
                              void* d_out, int out_size, void* d_ws, size_t ws_size,
                              hipStream_t stream) {
  const float* x     = (const float*)d_in[0];
  const int*   mask  = (const int*)d_in[1];
  const float* Wq    = (const float*)d_in[2];
  const float* bq    = (const float*)d_in[3];
  const float* Wk    = (const float*)d_in[4];
  const float* bk    = (const float*)d_in[5];
  const float* Wv    = (const float*)d_in[6];
  const float* bv    = (const float*)d_in[7];
  const float* Wo    = (const float*)d_in[8];
  const float* bo    = (const float*)d_in[9];
  const float* gamma = (const float*)d_in[10];
  const float* beta  = (const float*)d_in[11];

  char* ws = (char*)d_ws;
  unsigned short* xb    = (unsigned short*)(ws + WS_XB);
  unsigned short* wqb   = (unsigned short*)(ws + WS_WQ);
  unsigned short* wkb   = (unsigned short*)(ws + WS_WK);
  unsigned short* wvb   = (unsigned short*)(ws + WS_WV);
  unsigned short* wob   = (unsigned short*)(ws + WS_WO);
  unsigned short* q_ws  = (unsigned short*)(ws + WS_Q);
  unsigned short* k_ws  = (unsigned short*)(ws + WS_KK);
  unsigned short* vt_ws = (unsigned short*)(ws + WS_VT);
  float*          y_ws  = (float*)(ws + WS_Y);
  unsigned short* ctx   = (unsigned short*)d_out;

  const int nx4 = (BS_ * D_) / 4;
  const int nw4 = (D_ * D_) / 4;
  cvt_f32_bf16<<<(nx4 + 255) / 256, 256, 0, stream>>>(x,  xb,  nx4);
  cvt_f32_bf16<<<(nw4 + 255) / 256, 256, 0, stream>>>(Wq, wqb, nw4);
  cvt_f32_bf16<<<(nw4 + 255) / 256, 256, 0, stream>>>(Wk, wkb, nw4);
  cvt_f32_bf16<<<(nw4 + 255) / 256, 256, 0, stream>>>(Wv, wvb, nw4);
  cvt_f32_bf16<<<(nw4 + 255) / 256, 256, 0, stream>>>(Wo, wob, nw4);

  gemm_qkv<<<dim3(BS_ / BM, D_ / BN, 3), 256, 0, stream>>>(
      xb, wqb, bq, wkb, bk, wvb, bv, q_ws, k_ws, vt_ws);

  attn_kernel<<<dim3(16 * 64), 256, 0, stream>>>(   // 1024 blocks, swizzled
      q_ws, k_ws, vt_ws, mask, ctx);

  gemm_out<<<dim3(BS_ / BM, D_ / BN), 256, 0, stream>>>(
      ctx, wob, bo, x, y_ws);

  ln_kernel<<<BS_, 256, 0, stream>>>(y_ws, gamma, beta, (float*)d_out);
}

// Round 6
// 571.620 us; speedup vs baseline: 1.0027x; 1.0027x over previous
//
#include <hip/hip_runtime.h>

// Problem constants
#define D_  1024
#define S_  2048
#define B_  4
#define H_  16
#define HD_ 64
#define BS_ (B_*S_)   // 8192 rows

// GEMM tiling (m97 structure)
#define BM 128
#define BN 128
#define BK 32
#define NT (D_ / BK)   // 32 K-steps

typedef __attribute__((ext_vector_type(8))) short short8;   // 8 bf16 = 4 VGPRs
typedef __attribute__((ext_vector_type(4))) float floatx4;  // MFMA C/D
typedef __attribute__((ext_vector_type(4))) unsigned int uint4v;

typedef __attribute__((address_space(3))) unsigned int lds_uint;
typedef const __attribute__((address_space(1))) unsigned int glob_uint;

// Workspace layout (byte offsets), 72 MB total.
#define WS_XB ((size_t)0)            // 16 MB bf16 x
#define WS_WQ ((size_t)16 << 20)     // 2 MB bf16 Wq
#define WS_WK ((size_t)18 << 20)
#define WS_WV ((size_t)20 << 20)
#define WS_WO ((size_t)22 << 20)
#define WS_Q  ((size_t)24 << 20)     // 16 MB bf16 Q [b,h,s,hd]
#define WS_KK ((size_t)40 << 20)     // 16 MB bf16 K [b,h,s,hd]
#define WS_VT ((size_t)56 << 20)     // 16 MB bf16 V^T [b,h,hd,s]
#define WS_Y  WS_Q                   // y (fp32, 32 MB) overlays Q+K after attn

static __device__ __forceinline__ unsigned short f2bf(float f) {
  unsigned u = __builtin_bit_cast(unsigned, f);
  unsigned r = (u + 0x7fffu + ((u >> 16) & 1u)) >> 16;  // RNE
  return (unsigned short)r;
}

static __device__ __forceinline__ unsigned cvtpk_bf16(float lo, float hi) {
  unsigned r;
  asm("v_cvt_pk_bf16_f32 %0, %1, %2" : "=v"(r) : "v"(lo), "v"(hi));
  return r;
}

#define PSWAP(a, b) asm("v_permlane32_swap_b32 %0, %1" : "+v"(a), "+v"(b))

// ---------------------------------------------------------------------------
// Kernel 0: fp32 -> bf16 convert (RNE), 4 elements per thread.
// ---------------------------------------------------------------------------
__global__ __launch_bounds__(256) void cvt_f32_bf16(
    const float* __restrict__ src, unsigned short* __restrict__ dst, int n4)
{
  int i = blockIdx.x * 256 + threadIdx.x;
  if (i < n4) {
    float4 v = ((const float4*)src)[i];
    ushort4 o;
    o.x = f2bf(v.x); o.y = f2bf(v.y); o.z = f2bf(v.z); o.w = f2bf(v.w);
    ((ushort4*)dst)[i] = o;
  }
}

// ---------------------------------------------------------------------------
// Tiled GEMM mainloop (shared by gemm_qkv / gemm_out). m97 structure.
// ---------------------------------------------------------------------------
#define GEMM_MAINLOOP(Aptr, Bptr)                                              \
  __shared__ unsigned short lds[2][2][BM * BK];                                \
  const int tid  = threadIdx.x;                                                \
  const int wv   = tid >> 6;                                                   \
  const int lane = tid & 63;                                                   \
  const int c    = lane & 15;                                                  \
  const int quad = lane >> 4;                                                  \
  const int m0   = blockIdx.x * BM;                                            \
  const int n0   = blockIdx.y * BN;                                            \
  const int srow = lane >> 2;                                                  \
  const int scol = (lane & 3) * 8;                                             \
  const unsigned short* gA = (Aptr) + (size_t)(m0 + wv * 16 + srow) * D_ + scol;\
  const unsigned short* gB = (Bptr) + (size_t)(n0 + wv * 16 + srow) * D_ + scol;\
  const int lbase = (wv * 16) * BK;                                            \
  const int wr = (wv >> 1) * 64;                                               \
  const int wc = (wv & 1) * 64;                                                \
  floatx4 acc[4][4];                                                           \
  _Pragma("unroll")                                                            \
  for (int mi = 0; mi < 4; ++mi)                                               \
    _Pragma("unroll")                                                          \
    for (int ni = 0; ni < 4; ++ni) acc[mi][ni] = (floatx4){0.f,0.f,0.f,0.f};   \
  auto stage = [&](int buf, int t) {                                           \
    const size_t koff = (size_t)t * BK;                                        \
    _Pragma("unroll")                                                          \
    for (int j = 0; j < 2; ++j) {                                              \
      __builtin_amdgcn_global_load_lds(                                        \
          (glob_uint*)(gA + (size_t)j * 64 * D_ + koff),                       \
          (lds_uint*)&lds[buf][0][j * 64 * BK + lbase], 16, 0, 0);             \
      __builtin_amdgcn_global_load_lds(                                        \
          (glob_uint*)(gB + (size_t)j * 64 * D_ + koff),                       \
          (lds_uint*)&lds[buf][1][j * 64 * BK + lbase], 16, 0, 0);             \
    }                                                                          \
  };                                                                           \
  stage(0, 0);                                                                 \
  __syncthreads();                                                             \
  int cur = 0;                                                                 \
  for (int t = 0; t < NT; ++t) {                                               \
    if (t + 1 < NT) stage(cur ^ 1, t + 1);                                     \
    const unsigned short* LA = &lds[cur][0][0];                                \
    const unsigned short* LB = &lds[cur][1][0];                                \
    short8 af[4], bf[4];                                                       \
    _Pragma("unroll")                                                          \
    for (int i = 0; i < 4; ++i) {                                              \
      af[i] = *(const short8*)&LA[(wr + i * 16 + c) * BK + quad * 8];          \
      bf[i] = *(const short8*)&LB[(wc + i * 16 + c) * BK + quad * 8];          \
    }                                                                          \
    _Pragma("unroll")                                                          \
    for (int mi = 0; mi < 4; ++mi)                                             \
      _Pragma("unroll")                                                        \
      for (int ni = 0; ni < 4; ++ni)                                           \
        acc[mi][ni] = __builtin_amdgcn_mfma_f32_16x16x32_bf16(                 \
            af[mi], bf[ni], acc[mi][ni], 0, 0, 0);                             \
    __syncthreads();                                                           \
    cur ^= 1;                                                                  \
  }

// ---------------------------------------------------------------------------
// Kernel 1: QKV projection (tiled). mode = blockIdx.z:
//   0 -> Q [b,h,s,hd]; 1 -> K [b,h,s,hd]; 2 -> V^T [b,h,hd,s].
// ---------------------------------------------------------------------------
__global__ __launch_bounds__(256) void gemm_qkv(
    const unsigned short* __restrict__ X,
    const unsigned short* __restrict__ Wq, const float* __restrict__ bq,
    const unsigned short* __restrict__ Wk, const float* __restrict__ bk,
    const unsigned short* __restrict__ Wv, const float* __restrict__ bv,
    unsigned short* __restrict__ Qo, unsigned short* __restrict__ Ko,
    unsigned short* __restrict__ Vo)
{
  const int mode = blockIdx.z;
  const unsigned short* W = (mode == 0) ? Wq : ((mode == 1) ? Wk : Wv);
  const float* bias       = (mode == 0) ? bq : ((mode == 1) ? bk : bv);
  unsigned short* dst     = (mode == 0) ? Qo : ((mode == 1) ? Ko : Vo);

  GEMM_MAINLOOP(X, W)

  const int b = m0 >> 11;
  #pragma unroll
  for (int mi = 0; mi < 4; ++mi) {
    const int sb = (m0 & (S_ - 1)) + wr + mi * 16 + quad * 4;
    #pragma unroll
    for (int ni = 0; ni < 4; ++ni) {
      const int n   = n0 + wc + ni * 16 + c;
      const float bv_ = bias[n];
      const int h  = n >> 6;
      const int hd = n & 63;
      if (mode < 2) {
        size_t base = ((size_t)((b * H_ + h) * S_ + sb)) * HD_ + hd;
        #pragma unroll
        for (int r = 0; r < 4; ++r)
          dst[base + (size_t)r * HD_] = f2bf(acc[mi][ni][r] + bv_);
      } else {
        size_t base = ((size_t)((b * H_ + h) * HD_ + hd)) * S_ + sb;
        ushort4 o;
        o.x = f2bf(acc[mi][ni][0] + bv_);
        o.y = f2bf(acc[mi][ni][1] + bv_);
        o.z = f2bf(acc[mi][ni][2] + bv_);
        o.w = f2bf(acc[mi][ni][3] + bv_);
        *(ushort4*)&dst[base] = o;
      }
    }
  }
}

// ---------------------------------------------------------------------------
// Kernel 2 (v8): v7 register-prefetch structure + LDS occupancy clamp.
// v5b/v6/v7 all compiled to 60-64 VGPRs (occupancy heuristic targets
// 8 blocks/CU when LDS=0) -> load pipeline impossible -> ~13 serial
// L3-latency loads/iter = 14K cyc/iter = 370us. The 36KB clamp caps
// achievable occupancy at 4 blocks/CU (= the grid's actual residency:
// 1024 blocks / 256 CUs), moving the allocator's VGPR bucket to 128 so
// the written prefetch schedule can actually be register-allocated.
// Math/mapping identical to v6/v7 (verified).
// P-frag slot->k map: k = kc0 + (quad>>1)*16 + (quad&1)*4 + (e>>2)*8 + (e&3).
// V frag: two 8B loads at +0 / +8 elements.
// ---------------------------------------------------------------------------
__global__ __launch_bounds__(256)
void attn_kernel(
    const unsigned short* __restrict__ Q, const unsigned short* __restrict__ K,
    const unsigned short* __restrict__ Vt, const int* __restrict__ mask,
    unsigned short* __restrict__ ctx)
{
  __shared__ unsigned short occ_clamp[36 * 1024 / 2];  // occupancy clamp: 4 blk/CU
  if (threadIdx.x == ~0u) {                            // never true; keeps LDS alive
    asm volatile("" ::"v"(&occ_clamp[0]) : "memory");
  }

  const int wv   = threadIdx.x >> 6;
  const int lane = threadIdx.x & 63;
  const int c    = lane & 15;
  const int quad = lane >> 4;

  const int id = blockIdx.x;
  const int bh = (id & 7) + 8 * (id >> 7);   // bh%8 == id%8 (XCD co-location)
  const int qt = (id >> 3) & 15;
  const int b  = bh >> 4;
  const int h  = bh & 15;
  const int q0 = qt * 128 + wv * 32;         // 32 q-rows per wave

  const unsigned short* Qb = Q  + (size_t)bh * S_ * HD_;
  const unsigned short* Kb = K  + (size_t)bh * S_ * HD_;
  const unsigned short* Vb = Vt + (size_t)bh * HD_ * S_;
  const int* mrow = mask + b * S_;

  // Q as B-fragments (B-row j = q = lane&15)
  short8 bQ[2][2];
  #pragma unroll
  for (int s = 0; s < 2; ++s) {
    const unsigned short* qrow = Qb + (size_t)(q0 + s * 16 + c) * HD_;
    bQ[s][0] = *(const short8*)(qrow + quad * 8);
    bQ[s][1] = *(const short8*)(qrow + 32 + quad * 8);
  }

  floatx4 acc[2][4];
  #pragma unroll
  for (int s = 0; s < 2; ++s)
    #pragma unroll
    for (int d = 0; d < 4; ++d) acc[s][d] = (floatx4){0.f, 0.f, 0.f, 0.f};
  float lsum[2] = {0.f, 0.f};

  const int voff = (quad & 1) * 4 + (quad >> 1) * 16;

  auto loadK = [&](int kc0, short8 (&kfo)[2][2], int4 (&mko)[2]) {
    #pragma unroll
    for (int ct2 = 0; ct2 < 2; ++ct2) {
      const unsigned short* krow = Kb + (size_t)(kc0 + ct2 * 16 + c) * HD_;
      kfo[ct2][0] = *(const short8*)(krow + quad * 8);
      kfo[ct2][1] = *(const short8*)(krow + 32 + quad * 8);
      mko[ct2] = *(const int4*)(mrow + kc0 + ct2 * 16 + quad * 4);
    }
  };

  short8 kf[2][2];
  int4   mk[2];
  loadK(0, kf, mk);

  for (int idx = 0; idx < 64; ++idx) {
    const int kc0 = idx * 32;

    // ---- 1) issue V loads for the CURRENT chunk (independent of compute) --
    uint2 vl[4], vh[4];
    #pragma unroll
    for (int dt = 0; dt < 4; ++dt) {
      const unsigned short* vrow = Vb + (size_t)(dt * 16 + c) * S_ + kc0 + voff;
      vl[dt] = *(const uint2*)(vrow);        // k offsets +0..+3
      vh[dt] = *(const uint2*)(vrow + 8);    // k offsets +8..+11
    }

    // ---- 2) QK^T (swapped) from prefetched K frags ----
    floatx4 Cm[2][2];
    #pragma unroll
    for (int ct2 = 0; ct2 < 2; ++ct2) {
      floatx4 z0 = {0.f,0.f,0.f,0.f}, z1 = {0.f,0.f,0.f,0.f};
      z0 = __builtin_amdgcn_mfma_f32_16x16x32_bf16(kf[ct2][0], bQ[0][0], z0, 0, 0, 0);
      z1 = __builtin_amdgcn_mfma_f32_16x16x32_bf16(kf[ct2][0], bQ[1][0], z1, 0, 0, 0);
      z0 = __builtin_amdgcn_mfma_f32_16x16x32_bf16(kf[ct2][1], bQ[0][1], z0, 0, 0, 0);
      z1 = __builtin_amdgcn_mfma_f32_16x16x32_bf16(kf[ct2][1], bQ[1][1], z1, 0, 0, 0);
      Cm[0][ct2] = z0;
      Cm[1][ct2] = z1;
    }

    // ---- 3) prefetch NEXT chunk's K + mask into registers ----
    short8 kn[2][2];
    int4   mn[2];
    loadK((idx < 63) ? kc0 + 32 : 0, kn, mn);

    // ---- 4) mask + exp (static max) + lane-local l + pack ----
    unsigned w[2][2][2];
    #pragma unroll
    for (int ct2 = 0; ct2 < 2; ++ct2) {
      const float mb0 = (mk[ct2].x == 0) ? -1e30f : 0.f;
      const float mb1 = (mk[ct2].y == 0) ? -1e30f : 0.f;
      const float mb2 = (mk[ct2].z == 0) ? -1e30f : 0.f;
      const float mb3 = (mk[ct2].w == 0) ? -1e30f : 0.f;
      #pragma unroll
      for (int s = 0; s < 2; ++s) {
        float p0 = __expf(fmaf(Cm[s][ct2][0], 0.125f, mb0));
        float p1 = __expf(fmaf(Cm[s][ct2][1], 0.125f, mb1));
        float p2 = __expf(fmaf(Cm[s][ct2][2], 0.125f, mb2));
        float p3 = __expf(fmaf(Cm[s][ct2][3], 0.125f, mb3));
        lsum[s] += (p0 + p1) + (p2 + p3);
        w[s][ct2][0] = cvtpk_bf16(p0, p1);
        w[s][ct2][1] = cvtpk_bf16(p2, p3);
      }
    }

    // ---- 5) PV: P B-frags in-register; V A-frags shared by subtiles ----
    short8 pf[2];
    #pragma unroll
    for (int s = 0; s < 2; ++s) {
      unsigned a0 = w[s][0][0], a1 = w[s][0][1];
      unsigned b0 = w[s][1][0], b1 = w[s][1][1];
      PSWAP(a0, b0);
      PSWAP(a1, b1);
      uint4v pw = {a0, a1, b0, b1};
      pf[s] = __builtin_bit_cast(short8, pw);
    }
    #pragma unroll
    for (int dt = 0; dt < 4; ++dt) {
      uint4v vw = {vl[dt].x, vl[dt].y, vh[dt].x, vh[dt].y};
      short8 vf = __builtin_bit_cast(short8, vw);
      acc[0][dt] = __builtin_amdgcn_mfma_f32_16x16x32_bf16(vf, pf[0], acc[0][dt], 0, 0, 0);
      acc[1][dt] = __builtin_amdgcn_mfma_f32_16x16x32_bf16(vf, pf[1], acc[1][dt], 0, 0, 0);
    }

    // ---- 6) rotate prefetch registers ----
    #pragma unroll
    for (int ct2 = 0; ct2 < 2; ++ct2) {
      kf[ct2][0] = kn[ct2][0];
      kf[ct2][1] = kn[ct2][1];
      mk[ct2]    = mn[ct2];
    }
  }

  // ---- epilogue: cross-quad l reduce (only shuffles in the kernel) ----
  #pragma unroll
  for (int s = 0; s < 2; ++s) {
    float l = lsum[s];
    l += __shfl_xor(l, 16);
    l += __shfl_xor(l, 32);
    const float inv = 1.f / l;
    #pragma unroll
    for (int dt = 0; dt < 4; ++dt) {
      ushort4 o;
      o.x = f2bf(acc[s][dt][0] * inv);
      o.y = f2bf(acc[s][dt][1] * inv);
      o.z = f2bf(acc[s][dt][2] * inv);
      o.w = f2bf(acc[s][dt][3] * inv);
      *(ushort4*)&ctx[((size_t)(b * S_ + q0 + s * 16 + c)) * D_ +
                      h * HD_ + dt * 16 + quad * 4] = o;
    }
  }
}

// ---------------------------------------------------------------------------
// Kernel 3: out-proj + residual (tiled). y[m,n] = ctx@Wo.T + bo + x. y fp32.
// ---------------------------------------------------------------------------
__global__ __launch_bounds__(256) void gemm_out(
    const unsigned short* __restrict__ CTX, const unsigned short* __restrict__ W,
    const float* __restrict__ bo, const float* __restrict__ X,
    float* __restrict__ Y)
{
  GEMM_MAINLOOP(CTX, W)

  #pragma unroll
  for (int mi = 0; mi < 4; ++mi) {
    const int m = m0 + wr + mi * 16 + quad * 4;
    #pragma unroll
    for (int ni = 0; ni < 4; ++ni) {
      const int n = n0 + wc + ni * 16 + c;
      const float bias = bo[n];
      #pragma unroll
      for (int r = 0; r < 4; ++r)
        Y[(size_t)(m + r) * D_ + n] =
            acc[mi][ni][r] + bias + X[(size_t)(m + r) * D_ + n];
    }
  }
}

// ---------------------------------------------------------------------------
// Kernel 4: LayerNorm over last dim (1024). y fp32 in; OUTPUT FP32.
// ---------------------------------------------------------------------------
__global__ __launch_bounds__(256) void ln_kernel(
    const float* __restrict__ Y, const float* __restrict__ gamma,
    const float* __restrict__ beta, float* __restrict__ out)
{
  __shared__ float red[2][4];
  const int row  = blockIdx.x;
  const int tid  = threadIdx.x;
  const int wv   = tid >> 6;
  const int lane = tid & 63;
  const float* y = Y + (size_t)row * D_;

  float v[4];
  float sum = 0.f, sumsq = 0.f;
  #pragma unroll
  for (int i = 0; i < 4; ++i) {
    v[i] = y[tid + i * 256];
    sum += v[i];
    sumsq += v[i] * v[i];
  }
  #pragma unroll
  for (int off = 32; off > 0; off >>= 1) {
    sum   += __shfl_down(sum, off, 64);
    sumsq += __shfl_down(sumsq, off, 64);
  }
  if (lane == 0) { red[0][wv] = sum; red[1][wv] = sumsq; }
  __syncthreads();
  sum   = red[0][0] + red[0][1] + red[0][2] + red[0][3];
  sumsq = red[1][0] + red[1][1] + red[1][2] + red[1][3];

  const float mu   = sum * (1.f / D_);
  const float var  = sumsq * (1.f / D_) - mu * mu;
  const float rstd = rsqrtf(var + 1e-5f);

  #pragma unroll
  for (int i = 0; i < 4; ++i) {
    const int col = tid + i * 256;
    out[(size_t)row * D_ + col] = (v[i] - mu) * rstd * gamma[col] + beta[col];
  }
}

// ---------------------------------------------------------------------------
extern "C" void kernel_launch(void* const* d_in, const int* in_sizes, int n_in,
                              void* d_out, int out_size, void* d_ws, size_t ws_size,
                              hipStream_t stream) {
  const float* x     = (const float*)d_in[0];
  const int*   mask  = (const int*)d_in[1];
  const float* Wq    = (const float*)d_in[2];
  const float* bq    = (const float*)d_in[3];
  const float* Wk    = (const float*)d_in[4];
  const float* bk    = (const float*)d_in[5];
  const float* Wv    = (const float*)d_in[6];
  const float* bv    = (const float*)d_in[7];
  const float* Wo    = (const float*)d_in[8];
  const float* bo    = (const float*)d_in[9];
  const float* gamma = (const float*)d_in[10];
  const float* beta  = (const float*)d_in[11];

  char* ws = (char*)d_ws;
  unsigned short* xb    = (unsigned short*)(ws + WS_XB);
  unsigned short* wqb   = (unsigned short*)(ws + WS_WQ);
  unsigned short* wkb   = (unsigned short*)(ws + WS_WK);
  unsigned short* wvb   = (unsigned short*)(ws + WS_WV);
  unsigned short* wob   = (unsigned short*)(ws + WS_WO);
  unsigned short* q_ws  = (unsigned short*)(ws + WS_Q);
  unsigned short* k_ws  = (unsigned short*)(ws + WS_KK);
  unsigned short* vt_ws = (unsigned short*)(ws + WS_VT);
  float*          y_ws  = (float*)(ws + WS_Y);
  unsigned short* ctx   = (unsigned short*)d_out;

  const int nx4 = (BS_ * D_) / 4;
  const int nw4 = (D_ * D_) / 4;
  cvt_f32_bf16<<<(nx4 + 255) / 256, 256, 0, stream>>>(x,  xb,  nx4);
  cvt_f32_bf16<<<(nw4 + 255) / 256, 256, 0, stream>>>(Wq, wqb, nw4);
  cvt_f32_bf16<<<(nw4 + 255) / 256, 256, 0, stream>>>(Wk, wkb, nw4);
  cvt_f32_bf16<<<(nw4 + 255) / 256, 256, 0, stream>>>(Wv, wvb, nw4);
  cvt_f32_bf16<<<(nw4 + 255) / 256, 256, 0, stream>>>(Wo, wob, nw4);

  gemm_qkv<<<dim3(BS_ / BM, D_ / BN, 3), 256, 0, stream>>>(
      xb, wqb, bq, wkb, bk, wvb, bv, q_ws, k_ws, vt_ws);

  attn_kernel<<<dim3(16 * 64), 256, 0, stream>>>(   // 1024 blocks, swizzled
      q_ws, k_ws, vt_ws, mask, ctx);

  gemm_out<<<dim3(BS_ / BM, D_ / BN), 256, 0, stream>>>(
      ctx, wob, bo, x, y_ws);

  ln_kernel<<<BS_, 256, 0, stream>>>(y_ws, gamma, beta, (float*)d_out);
}

// Round 7
// 347.168 us; speedup vs baseline: 1.6509x; 1.6465x over previous
//
#include <hip/hip_runtime.h>

// Problem constants
#define D_  1024
#define S_  2048
#define B_  4
#define H_  16
#define HD_ 64
#define BS_ (B_*S_)   // 8192 rows

// GEMM tiling (m97 structure)
#define BM 128
#define BN 128
#define BK 32
#define NT (D_ / BK)   // 32 K-steps

typedef __attribute__((ext_vector_type(8))) short short8;   // 8 bf16 = 4 VGPRs
typedef __attribute__((ext_vector_type(4))) float floatx4;  // MFMA C/D
typedef __attribute__((ext_vector_type(4))) unsigned int uint4v;

typedef __attribute__((address_space(3))) unsigned int lds_uint;
typedef const __attribute__((address_space(1))) unsigned int glob_uint;

// Workspace layout (byte offsets), 72 MB total.
#define WS_XB ((size_t)0)            // 16 MB bf16 x
#define WS_WQ ((size_t)16 << 20)     // 2 MB bf16 Wq
#define WS_WK ((size_t)18 << 20)
#define WS_WV ((size_t)20 << 20)
#define WS_WO ((size_t)22 << 20)
#define WS_Q  ((size_t)24 << 20)     // 16 MB bf16 Q [b,h,s,hd]
#define WS_KK ((size_t)40 << 20)     // 16 MB bf16 K [b,h,s,hd]
#define WS_VT ((size_t)56 << 20)     // 16 MB bf16 V^T [b,h,hd,s]
#define WS_Y  WS_Q                   // y (fp32, 32 MB) overlays Q+K after attn

static __device__ __forceinline__ unsigned short f2bf(float f) {
  unsigned u = __builtin_bit_cast(unsigned, f);
  unsigned r = (u + 0x7fffu + ((u >> 16) & 1u)) >> 16;  // RNE
  return (unsigned short)r;
}

static __device__ __forceinline__ unsigned cvtpk_bf16(float lo, float hi) {
  unsigned r;
  asm("v_cvt_pk_bf16_f32 %0, %1, %2" : "=v"(r) : "v"(lo), "v"(hi));
  return r;
}

#define PSWAP(a, b) asm("v_permlane32_swap_b32 %0, %1" : "+v"(a), "+v"(b))

// ---------------------------------------------------------------------------
// Kernel 0: fp32 -> bf16 convert (RNE), 4 elements per thread.
// ---------------------------------------------------------------------------
__global__ __launch_bounds__(256) void cvt_f32_bf16(
    const float* __restrict__ src, unsigned short* __restrict__ dst, int n4)
{
  int i = blockIdx.x * 256 + threadIdx.x;
  if (i < n4) {
    float4 v = ((const float4*)src)[i];
    ushort4 o;
    o.x = f2bf(v.x); o.y = f2bf(v.y); o.z = f2bf(v.z); o.w = f2bf(v.w);
    ((ushort4*)dst)[i] = o;
  }
}

// ---------------------------------------------------------------------------
// Tiled GEMM mainloop (shared by gemm_qkv / gemm_out). m97 structure.
// ---------------------------------------------------------------------------
#define GEMM_MAINLOOP(Aptr, Bptr)                                              \
  __shared__ unsigned short lds[2][2][BM * BK];                                \
  const int tid  = threadIdx.x;                                                \
  const int wv   = tid >> 6;                                                   \
  const int lane = tid & 63;                                                   \
  const int c    = lane & 15;                                                  \
  const int quad = lane >> 4;                                                  \
  const int m0   = blockIdx.x * BM;                                            \
  const int n0   = blockIdx.y * BN;                                            \
  const int srow = lane >> 2;                                                  \
  const int scol = (lane & 3) * 8;                                             \
  const unsigned short* gA = (Aptr) + (size_t)(m0 + wv * 16 + srow) * D_ + scol;\
  const unsigned short* gB = (Bptr) + (size_t)(n0 + wv * 16 + srow) * D_ + scol;\
  const int lbase = (wv * 16) * BK;                                            \
  const int wr = (wv >> 1) * 64;                                               \
  const int wc = (wv & 1) * 64;                                                \
  floatx4 acc[4][4];                                                           \
  _Pragma("unroll")                                                            \
  for (int mi = 0; mi < 4; ++mi)                                               \
    _Pragma("unroll")                                                          \
    for (int ni = 0; ni < 4; ++ni) acc[mi][ni] = (floatx4){0.f,0.f,0.f,0.f};   \
  auto stage = [&](int buf, int t) {                                           \
    const size_t koff = (size_t)t * BK;                                        \
    _Pragma("unroll")                                                          \
    for (int j = 0; j < 2; ++j) {                                              \
      __builtin_amdgcn_global_load_lds(                                        \
          (glob_uint*)(gA + (size_t)j * 64 * D_ + koff),                       \
          (lds_uint*)&lds[buf][0][j * 64 * BK + lbase], 16, 0, 0);             \
      __builtin_amdgcn_global_load_lds(                                        \
          (glob_uint*)(gB + (size_t)j * 64 * D_ + koff),                       \
          (lds_uint*)&lds[buf][1][j * 64 * BK + lbase], 16, 0, 0);             \
    }                                                                          \
  };                                                                           \
  stage(0, 0);                                                                 \
  __syncthreads();                                                             \
  int cur = 0;                                                                 \
  for (int t = 0; t < NT; ++t) {                                               \
    if (t + 1 < NT) stage(cur ^ 1, t + 1);                                     \
    const unsigned short* LA = &lds[cur][0][0];                                \
    const unsigned short* LB = &lds[cur][1][0];                                \
    short8 af[4], bf[4];                                                       \
    _Pragma("unroll")                                                          \
    for (int i = 0; i < 4; ++i) {                                              \
      af[i] = *(const short8*)&LA[(wr + i * 16 + c) * BK + quad * 8];          \
      bf[i] = *(const short8*)&LB[(wc + i * 16 + c) * BK + quad * 8];          \
    }                                                                          \
    _Pragma("unroll")                                                          \
    for (int mi = 0; mi < 4; ++mi)                                             \
      _Pragma("unroll")                                                        \
      for (int ni = 0; ni < 4; ++ni)                                           \
        acc[mi][ni] = __builtin_amdgcn_mfma_f32_16x16x32_bf16(                 \
            af[mi], bf[ni], acc[mi][ni], 0, 0, 0);                             \
    __syncthreads();                                                           \
    cur ^= 1;                                                                  \
  }

// ---------------------------------------------------------------------------
// Kernel 1: QKV projection (tiled). mode = blockIdx.z:
//   0 -> Q [b,h,s,hd]; 1 -> K [b,h,s,hd]; 2 -> V^T [b,h,hd,s].
// ---------------------------------------------------------------------------
__global__ __launch_bounds__(256) void gemm_qkv(
    const unsigned short* __restrict__ X,
    const unsigned short* __restrict__ Wq, const float* __restrict__ bq,
    const unsigned short* __restrict__ Wk, const float* __restrict__ bk,
    const unsigned short* __restrict__ Wv, const float* __restrict__ bv,
    unsigned short* __restrict__ Qo, unsigned short* __restrict__ Ko,
    unsigned short* __restrict__ Vo)
{
  const int mode = blockIdx.z;
  const unsigned short* W = (mode == 0) ? Wq : ((mode == 1) ? Wk : Wv);
  const float* bias       = (mode == 0) ? bq : ((mode == 1) ? bk : bv);
  unsigned short* dst     = (mode == 0) ? Qo : ((mode == 1) ? Ko : Vo);

  GEMM_MAINLOOP(X, W)

  const int b = m0 >> 11;
  #pragma unroll
  for (int mi = 0; mi < 4; ++mi) {
    const int sb = (m0 & (S_ - 1)) + wr + mi * 16 + quad * 4;
    #pragma unroll
    for (int ni = 0; ni < 4; ++ni) {
      const int n   = n0 + wc + ni * 16 + c;
      const float bv_ = bias[n];
      const int h  = n >> 6;
      const int hd = n & 63;
      if (mode < 2) {
        size_t base = ((size_t)((b * H_ + h) * S_ + sb)) * HD_ + hd;
        #pragma unroll
        for (int r = 0; r < 4; ++r)
          dst[base + (size_t)r * HD_] = f2bf(acc[mi][ni][r] + bv_);
      } else {
        size_t base = ((size_t)((b * H_ + h) * HD_ + hd)) * S_ + sb;
        ushort4 o;
        o.x = f2bf(acc[mi][ni][0] + bv_);
        o.y = f2bf(acc[mi][ni][1] + bv_);
        o.z = f2bf(acc[mi][ni][2] + bv_);
        o.w = f2bf(acc[mi][ni][3] + bv_);
        *(ushort4*)&dst[base] = o;
      }
    }
  }
}

// ---------------------------------------------------------------------------
// Kernel 2 (v9): flash attention, LDS-staged K/V via global_load_lds with
// XOR-swizzled layout (T2), double-buffered, one barrier per 64-k tile.
// All 4 waves of a block share the same (bh, K/V tiles) -> staging cuts the
// per-wave global load count 4x and moves the pipeline to the proven
// GEMM-style global_load_lds + vmcnt-drain-at-barrier schedule. Registers:
// softmax/P path identical to verified v5b/v6 (swapped QK^T, static max,
// cvt_pk + permlane32_swap in-register P).
//
// LDS layout (per K and V tile, 64 rows x 64 bf16 cols = 8 KB):
//   16B-chunk XOR swizzle: phys_chunk = log_chunk ^ (row & 7)
//   - stage (linear dest): chunk P (0..511): row = P>>3, and the SOURCE
//     global 16B chunk is (P&7) ^ (row&7)  [inverse == forward, involution]
//   - K read (lane c,quad; kt2, half): row = kt2*16+c,
//     addr_ushort = row*64 + ((half*4+quad) ^ (row&7))*8      (2-way, free)
//   - V read (lane c,quad; dt, ch): row = dt*16+c, c0 = ch*4+(quad>>1)*2,
//     two 8B reads at ((c0)^(row&7))*8 + (quad&1)*4 and ((c0+1)^...)
// Buffers declared 5120 ushorts (4096 used): total LDS = 40 KB -> hard cap
// 4 blocks/CU (== grid residency 1024/256), so the allocator's VGPR bucket
// is 128 and nothing real is lost.
// ---------------------------------------------------------------------------
__global__ __launch_bounds__(256)
void attn_kernel(
    const unsigned short* __restrict__ Q, const unsigned short* __restrict__ K,
    const unsigned short* __restrict__ Vt, const int* __restrict__ mask,
    unsigned short* __restrict__ ctx)
{
  __shared__ unsigned short Kl[2][5120];  // 4096 used + pad -> 40KB total
  __shared__ unsigned short Vl[2][5120];

  const int wv   = threadIdx.x >> 6;
  const int lane = threadIdx.x & 63;
  const int c    = lane & 15;
  const int quad = lane >> 4;

  const int id = blockIdx.x;
  const int bh = (id & 7) + 8 * (id >> 7);   // bh%8 == id%8 (XCD co-location)
  const int qt = (id >> 3) & 15;
  const int b  = bh >> 4;
  const int h  = bh & 15;
  const int q0 = qt * 128 + wv * 32;         // 32 q-rows per wave

  const unsigned short* Qb = Q  + (size_t)bh * S_ * HD_;
  const unsigned short* Kb = K  + (size_t)bh * S_ * HD_;
  const unsigned short* Vb = Vt + (size_t)bh * HD_ * S_;
  const int* mrow = mask + b * S_;

  // Q as B-fragments (B-row j = q = lane&15)
  short8 bQ[2][2];
  #pragma unroll
  for (int s = 0; s < 2; ++s) {
    const unsigned short* qrow = Qb + (size_t)(q0 + s * 16 + c) * HD_;
    bQ[s][0] = *(const short8*)(qrow + quad * 8);
    bQ[s][1] = *(const short8*)(qrow + 32 + quad * 8);
  }

  floatx4 acc[2][4];
  #pragma unroll
  for (int s = 0; s < 2; ++s)
    #pragma unroll
    for (int d = 0; d < 4; ++d) acc[s][d] = (floatx4){0.f, 0.f, 0.f, 0.f};
  float lsum[2] = {0.f, 0.f};

  // Stage one 64-k tile of K and V into LDS buffer `buf`.
  // Chunk index P = j*256 + wv*64 + lane; dest base is wave-uniform
  // (HW adds lane*16); source chunk is XOR-permuted so that the LINEAR
  // LDS write realizes the swizzled layout.
  auto stageKV = [&](int buf, int kp0) {
    #pragma unroll
    for (int j = 0; j < 2; ++j) {
      const int Pb  = j * 256 + (wv << 6);
      const int P   = Pb + lane;
      const int row = P >> 3;
      const int c8  = (P & 7) ^ (row & 7);
      __builtin_amdgcn_global_load_lds(
          (glob_uint*)(Kb + (size_t)(kp0 + row) * HD_ + c8 * 8),
          (lds_uint*)&Kl[buf][Pb * 8], 16, 0, 0);
      __builtin_amdgcn_global_load_lds(
          (glob_uint*)(Vb + (size_t)row * S_ + kp0 + c8 * 8),
          (lds_uint*)&Vl[buf][Pb * 8], 16, 0, 0);
    }
  };

  stageKV(0, 0);
  __syncthreads();
  int cur = 0;

  for (int t = 0; t < S_ / 64; ++t) {
    const int kp0 = t * 64;
    if (t + 1 < S_ / 64) stageKV(cur ^ 1, kp0 + 64);

    // mask words for this tile (L2-resident; latency hides under QK^T)
    int4 mk4[4];
    #pragma unroll
    for (int ct = 0; ct < 4; ++ct)
      mk4[ct] = *(const int4*)(mrow + kp0 + ct * 16 + quad * 4);

    // ---- QK^T (swapped) from swizzled LDS K tile ----
    floatx4 Cm[2][4];
    #pragma unroll
    for (int kt2 = 0; kt2 < 4; ++kt2) {
      const int krow = kt2 * 16 + c;
      const int sw   = krow & 7;
      short8 k0 = *(const short8*)&Kl[cur][krow * 64 + ((quad) ^ sw) * 8];
      short8 k1 = *(const short8*)&Kl[cur][krow * 64 + ((4 + quad) ^ sw) * 8];
      floatx4 z0 = {0.f,0.f,0.f,0.f}, z1 = {0.f,0.f,0.f,0.f};
      z0 = __builtin_amdgcn_mfma_f32_16x16x32_bf16(k0, bQ[0][0], z0, 0, 0, 0);
      z1 = __builtin_amdgcn_mfma_f32_16x16x32_bf16(k0, bQ[1][0], z1, 0, 0, 0);
      z0 = __builtin_amdgcn_mfma_f32_16x16x32_bf16(k1, bQ[0][1], z0, 0, 0, 0);
      z1 = __builtin_amdgcn_mfma_f32_16x16x32_bf16(k1, bQ[1][1], z1, 0, 0, 0);
      Cm[0][kt2] = z0;
      Cm[1][kt2] = z1;
    }

    // ---- mask + exp (static max) + lane-local l + pack to bf16 pairs ----
    unsigned w[2][4][2];
    #pragma unroll
    for (int ct = 0; ct < 4; ++ct) {
      const float mb0 = (mk4[ct].x == 0) ? -1e30f : 0.f;
      const float mb1 = (mk4[ct].y == 0) ? -1e30f : 0.f;
      const float mb2 = (mk4[ct].z == 0) ? -1e30f : 0.f;
      const float mb3 = (mk4[ct].w == 0) ? -1e30f : 0.f;
      #pragma unroll
      for (int s = 0; s < 2; ++s) {
        float p0 = __expf(fmaf(Cm[s][ct][0], 0.125f, mb0));
        float p1 = __expf(fmaf(Cm[s][ct][1], 0.125f, mb1));
        float p2 = __expf(fmaf(Cm[s][ct][2], 0.125f, mb2));
        float p3 = __expf(fmaf(Cm[s][ct][3], 0.125f, mb3));
        lsum[s] += (p0 + p1) + (p2 + p3);
        w[s][ct][0] = cvtpk_bf16(p0, p1);
        w[s][ct][1] = cvtpk_bf16(p2, p3);
      }
    }

    // ---- PV: P B-frags in-register; V A-frags from swizzled LDS ----
    #pragma unroll
    for (int ch = 0; ch < 2; ++ch) {
      short8 pf[2];
      #pragma unroll
      for (int s = 0; s < 2; ++s) {
        unsigned a0 = w[s][2 * ch][0],     a1 = w[s][2 * ch][1];
        unsigned b0 = w[s][2 * ch + 1][0], b1 = w[s][2 * ch + 1][1];
        PSWAP(a0, b0);
        PSWAP(a1, b1);
        uint4v pw = {a0, a1, b0, b1};
        pf[s] = __builtin_bit_cast(short8, pw);
      }
      const int c0 = ch * 4 + (quad >> 1) * 2;   // first 16B chunk of 8B pair
      const int h0 = (quad & 1) * 4;             // 8B half within chunk (ushorts)
      #pragma unroll
      for (int dt = 0; dt < 4; ++dt) {
        const int vrow = dt * 16 + c;
        const int sw   = vrow & 7;
        uint2 vlo = *(const uint2*)&Vl[cur][vrow * 64 + ((c0)     ^ sw) * 8 + h0];
        uint2 vhi = *(const uint2*)&Vl[cur][vrow * 64 + ((c0 + 1) ^ sw) * 8 + h0];
        uint4v vw = {vlo.x, vlo.y, vhi.x, vhi.y};
        short8 vf = __builtin_bit_cast(short8, vw);
        acc[0][dt] = __builtin_amdgcn_mfma_f32_16x16x32_bf16(vf, pf[0], acc[0][dt], 0, 0, 0);
        acc[1][dt] = __builtin_amdgcn_mfma_f32_16x16x32_bf16(vf, pf[1], acc[1][dt], 0, 0, 0);
      }
    }

    __syncthreads();
    cur ^= 1;
  }

  // ---- epilogue: cross-quad l reduce (only shuffles in the kernel) ----
  #pragma unroll
  for (int s = 0; s < 2; ++s) {
    float l = lsum[s];
    l += __shfl_xor(l, 16);
    l += __shfl_xor(l, 32);
    const float inv = 1.f / l;
    #pragma unroll
    for (int dt = 0; dt < 4; ++dt) {
      ushort4 o;
      o.x = f2bf(acc[s][dt][0] * inv);
      o.y = f2bf(acc[s][dt][1] * inv);
      o.z = f2bf(acc[s][dt][2] * inv);
      o.w = f2bf(acc[s][dt][3] * inv);
      *(ushort4*)&ctx[((size_t)(b * S_ + q0 + s * 16 + c)) * D_ +
                      h * HD_ + dt * 16 + quad * 4] = o;
    }
  }
}

// ---------------------------------------------------------------------------
// Kernel 3: out-proj + residual (tiled). y[m,n] = ctx@Wo.T + bo + x. y fp32.
// ---------------------------------------------------------------------------
__global__ __launch_bounds__(256) void gemm_out(
    const unsigned short* __restrict__ CTX, const unsigned short* __restrict__ W,
    const float* __restrict__ bo, const float* __restrict__ X,
    float* __restrict__ Y)
{
  GEMM_MAINLOOP(CTX, W)

  #pragma unroll
  for (int mi = 0; mi < 4; ++mi) {
    const int m = m0 + wr + mi * 16 + quad * 4;
    #pragma unroll
    for (int ni = 0; ni < 4; ++ni) {
      const int n = n0 + wc + ni * 16 + c;
      const float bias = bo[n];
      #pragma unroll
      for (int r = 0; r < 4; ++r)
        Y[(size_t)(m + r) * D_ + n] =
            acc[mi][ni][r] + bias + X[(size_t)(m + r) * D_ + n];
    }
  }
}

// ---------------------------------------------------------------------------
// Kernel 4: LayerNorm over last dim (1024). y fp32 in; OUTPUT FP32.
// ---------------------------------------------------------------------------
__global__ __launch_bounds__(256) void ln_kernel(
    const float* __restrict__ Y, const float* __restrict__ gamma,
    const float* __restrict__ beta, float* __restrict__ out)
{
  __shared__ float red[2][4];
  const int row  = blockIdx.x;
  const int tid  = threadIdx.x;
  const int wv   = tid >> 6;
  const int lane = tid & 63;
  const float* y = Y + (size_t)row * D_;

  float v[4];
  float sum = 0.f, sumsq = 0.f;
  #pragma unroll
  for (int i = 0; i < 4; ++i) {
    v[i] = y[tid + i * 256];
    sum += v[i];
    sumsq += v[i] * v[i];
  }
  #pragma unroll
  for (int off = 32; off > 0; off >>= 1) {
    sum   += __shfl_down(sum, off, 64);
    sumsq += __shfl_down(sumsq, off, 64);
  }
  if (lane == 0) { red[0][wv] = sum; red[1][wv] = sumsq; }
  __syncthreads();
  sum   = red[0][0] + red[0][1] + red[0][2] + red[0][3];
  sumsq = red[1][0] + red[1][1] + red[1][2] + red[1][3];

  const float mu   = sum * (1.f / D_);
  const float var  = sumsq * (1.f / D_) - mu * mu;
  const float rstd = rsqrtf(var + 1e-5f);

  #pragma unroll
  for (int i = 0; i < 4; ++i) {
    const int col = tid + i * 256;
    out[(size_t)row * D_ + col] = (v[i] - mu) * rstd * gamma[col] + beta[col];
  }
}

// ---------------------------------------------------------------------------
extern "C" void kernel_launch(void* const* d_in, const int* in_sizes, int n_in,
                              void* d_out, int out_size, void* d_ws, size_t ws_size,
                              hipStream_t stream) {
  const float* x     = (const float*)d_in[0];
  const int*   mask  = (const int*)d_in[1];
  const float* Wq    = (const float*)d_in[2];
  const float* bq    = (const float*)d_in[3];
  const float* Wk    = (const float*)d_in[4];
  const float* bk    = (const float*)d_in[5];
  const float* Wv    = (const float*)d_in[6];
  const float* bv    = (const float*)d_in[7];
  const float* Wo    = (const float*)d_in[8];
  const float* bo    = (const float*)d_in[9];
  const float* gamma = (const float*)d_in[10];
  const float* beta  = (const float*)d_in[11];

  char* ws = (char*)d_ws;
  unsigned short* xb    = (unsigned short*)(ws + WS_XB);
  unsigned short* wqb   = (unsigned short*)(ws + WS_WQ);
  unsigned short* wkb   = (unsigned short*)(ws + WS_WK);
  unsigned short* wvb   = (unsigned short*)(ws + WS_WV);
  unsigned short* wob   = (unsigned short*)(ws + WS_WO);
  unsigned short* q_ws  = (unsigned short*)(ws + WS_Q);
  unsigned short* k_ws  = (unsigned short*)(ws + WS_KK);
  unsigned short* vt_ws = (unsigned short*)(ws + WS_VT);
  float*          y_ws  = (float*)(ws + WS_Y);
  unsigned short* ctx   = (unsigned short*)d_out;

  const int nx4 = (BS_ * D_) / 4;
  const int nw4 = (D_ * D_) / 4;
  cvt_f32_bf16<<<(nx4 + 255) / 256, 256, 0, stream>>>(x,  xb,  nx4);
  cvt_f32_bf16<<<(nw4 + 255) / 256, 256, 0, stream>>>(Wq, wqb, nw4);
  cvt_f32_bf16<<<(nw4 + 255) / 256, 256, 0, stream>>>(Wk, wkb, nw4);
  cvt_f32_bf16<<<(nw4 + 255) / 256, 256, 0, stream>>>(Wv, wvb, nw4);
  cvt_f32_bf16<<<(nw4 + 255) / 256, 256, 0, stream>>>(Wo, wob, nw4);

  gemm_qkv<<<dim3(BS_ / BM, D_ / BN, 3), 256, 0, stream>>>(
      xb, wqb, bq, wkb, bk, wvb, bv, q_ws, k_ws, vt_ws);

  attn_kernel<<<dim3(16 * 64), 256, 0, stream>>>(   // 1024 blocks, swizzled
      q_ws, k_ws, vt_ws, mask, ctx);

  gemm_out<<<dim3(BS_ / BM, D_ / BN), 256, 0, stream>>>(
      ctx, wob, bo, x, y_ws);

  ln_kernel<<<BS_, 256, 0, stream>>>(y_ws, gamma, beta, (float*)d_out);
}

// Round 8
// 329.476 us; speedup vs baseline: 1.7396x; 1.0537x over previous
//
#include <hip/hip_runtime.h>

// Problem constants
#define D_  1024
#define S_  2048
#define B_  4
#define H_  16
#define HD_ 64
#define BS_ (B_*S_)   // 8192 rows

// GEMM tiling (m97 structure)
#define BM 128
#define BN 128
#define BK 32
#define NT (D_ / BK)   // 32 K-steps

typedef __attribute__((ext_vector_type(8))) short short8;   // 8 bf16 = 4 VGPRs
typedef __attribute__((ext_vector_type(4))) float floatx4;  // MFMA C/D
typedef __attribute__((ext_vector_type(4))) unsigned int uint4v;

typedef __attribute__((address_space(3))) unsigned int lds_uint;
typedef const __attribute__((address_space(1))) unsigned int glob_uint;

// Workspace layout (byte offsets), 72 MB total.
#define WS_XB ((size_t)0)            // 16 MB bf16 x
#define WS_WQ ((size_t)16 << 20)     // 2 MB bf16 Wq
#define WS_WK ((size_t)18 << 20)
#define WS_WV ((size_t)20 << 20)
#define WS_WO ((size_t)22 << 20)
#define WS_Q  ((size_t)24 << 20)     // 16 MB bf16 Q [b,h,s,hd]
#define WS_KK ((size_t)40 << 20)     // 16 MB bf16 K [b,h,s,hd]
#define WS_VT ((size_t)56 << 20)     // 16 MB bf16 V^T [b,h,hd,s]
#define WS_Y  WS_Q                   // y (fp32, 32 MB) overlays Q+K after attn

static __device__ __forceinline__ unsigned short f2bf(float f) {
  unsigned u = __builtin_bit_cast(unsigned, f);
  unsigned r = (u + 0x7fffu + ((u >> 16) & 1u)) >> 16;  // RNE
  return (unsigned short)r;
}

static __device__ __forceinline__ unsigned cvtpk_bf16(float lo, float hi) {
  unsigned r;
  asm("v_cvt_pk_bf16_f32 %0, %1, %2" : "=v"(r) : "v"(lo), "v"(hi));
  return r;
}

static __device__ __forceinline__ float exp2_fast(float x) {
  float r;
  asm("v_exp_f32 %0, %1" : "=v"(r) : "v"(x));   // D = 2^S0
  return r;
}

#define PSWAP(a, b) asm("v_permlane32_swap_b32 %0, %1" : "+v"(a), "+v"(b))

// ---------------------------------------------------------------------------
// Kernel 0: fp32 -> bf16 convert (RNE), 4 elements per thread.
// ---------------------------------------------------------------------------
__global__ __launch_bounds__(256) void cvt_f32_bf16(
    const float* __restrict__ src, unsigned short* __restrict__ dst, int n4)
{
  int i = blockIdx.x * 256 + threadIdx.x;
  if (i < n4) {
    float4 v = ((const float4*)src)[i];
    ushort4 o;
    o.x = f2bf(v.x); o.y = f2bf(v.y); o.z = f2bf(v.z); o.w = f2bf(v.w);
    ((ushort4*)dst)[i] = o;
  }
}

// ---------------------------------------------------------------------------
// Tiled GEMM mainloop (shared by gemm_qkv / gemm_out). m97 structure.
// ---------------------------------------------------------------------------
#define GEMM_MAINLOOP(Aptr, Bptr)                                              \
  __shared__ unsigned short lds[2][2][BM * BK];                                \
  const int tid  = threadIdx.x;                                                \
  const int wv   = tid >> 6;                                                   \
  const int lane = tid & 63;                                                   \
  const int c    = lane & 15;                                                  \
  const int quad = lane >> 4;                                                  \
  const int m0   = blockIdx.x * BM;                                            \
  const int n0   = blockIdx.y * BN;                                            \
  const int srow = lane >> 2;                                                  \
  const int scol = (lane & 3) * 8;                                             \
  const unsigned short* gA = (Aptr) + (size_t)(m0 + wv * 16 + srow) * D_ + scol;\
  const unsigned short* gB = (Bptr) + (size_t)(n0 + wv * 16 + srow) * D_ + scol;\
  const int lbase = (wv * 16) * BK;                                            \
  const int wr = (wv >> 1) * 64;                                               \
  const int wc = (wv & 1) * 64;                                                \
  floatx4 acc[4][4];                                                           \
  _Pragma("unroll")                                                            \
  for (int mi = 0; mi < 4; ++mi)                                               \
    _Pragma("unroll")                                                          \
    for (int ni = 0; ni < 4; ++ni) acc[mi][ni] = (floatx4){0.f,0.f,0.f,0.f};   \
  auto stage = [&](int buf, int t) {                                           \
    const size_t koff = (size_t)t * BK;                                        \
    _Pragma("unroll")                                                          \
    for (int j = 0; j < 2; ++j) {                                              \
      __builtin_amdgcn_global_load_lds(                                        \
          (glob_uint*)(gA + (size_t)j * 64 * D_ + koff),                       \
          (lds_uint*)&lds[buf][0][j * 64 * BK + lbase], 16, 0, 0);             \
      __builtin_amdgcn_global_load_lds(                                        \
          (glob_uint*)(gB + (size_t)j * 64 * D_ + koff),                       \
          (lds_uint*)&lds[buf][1][j * 64 * BK + lbase], 16, 0, 0);             \
    }                                                                          \
  };                                                                           \
  stage(0, 0);                                                                 \
  __syncthreads();                                                             \
  int cur = 0;                                                                 \
  for (int t = 0; t < NT; ++t) {                                               \
    if (t + 1 < NT) stage(cur ^ 1, t + 1);                                     \
    const unsigned short* LA = &lds[cur][0][0];                                \
    const unsigned short* LB = &lds[cur][1][0];                                \
    short8 af[4], bf[4];                                                       \
    _Pragma("unroll")                                                          \
    for (int i = 0; i < 4; ++i) {                                              \
      af[i] = *(const short8*)&LA[(wr + i * 16 + c) * BK + quad * 8];          \
      bf[i] = *(const short8*)&LB[(wc + i * 16 + c) * BK + quad * 8];          \
    }                                                                          \
    _Pragma("unroll")                                                          \
    for (int mi = 0; mi < 4; ++mi)                                             \
      _Pragma("unroll")                                                        \
      for (int ni = 0; ni < 4; ++ni)                                           \
        acc[mi][ni] = __builtin_amdgcn_mfma_f32_16x16x32_bf16(                 \
            af[mi], bf[ni], acc[mi][ni], 0, 0, 0);                             \
    __syncthreads();                                                           \
    cur ^= 1;                                                                  \
  }

// ---------------------------------------------------------------------------
// Kernel 1: QKV projection (tiled). mode = blockIdx.z:
//   0 -> Q [b,h,s,hd]; 1 -> K [b,h,s,hd]; 2 -> V^T [b,h,hd,s].
// ---------------------------------------------------------------------------
__global__ __launch_bounds__(256) void gemm_qkv(
    const unsigned short* __restrict__ X,
    const unsigned short* __restrict__ Wq, const float* __restrict__ bq,
    const unsigned short* __restrict__ Wk, const float* __restrict__ bk,
    const unsigned short* __restrict__ Wv, const float* __restrict__ bv,
    unsigned short* __restrict__ Qo, unsigned short* __restrict__ Ko,
    unsigned short* __restrict__ Vo)
{
  const int mode = blockIdx.z;
  const unsigned short* W = (mode == 0) ? Wq : ((mode == 1) ? Wk : Wv);
  const float* bias       = (mode == 0) ? bq : ((mode == 1) ? bk : bv);
  unsigned short* dst     = (mode == 0) ? Qo : ((mode == 1) ? Ko : Vo);

  GEMM_MAINLOOP(X, W)

  const int b = m0 >> 11;
  #pragma unroll
  for (int mi = 0; mi < 4; ++mi) {
    const int sb = (m0 & (S_ - 1)) + wr + mi * 16 + quad * 4;
    #pragma unroll
    for (int ni = 0; ni < 4; ++ni) {
      const int n   = n0 + wc + ni * 16 + c;
      const float bv_ = bias[n];
      const int h  = n >> 6;
      const int hd = n & 63;
      if (mode < 2) {
        size_t base = ((size_t)((b * H_ + h) * S_ + sb)) * HD_ + hd;
        #pragma unroll
        for (int r = 0; r < 4; ++r)
          dst[base + (size_t)r * HD_] = f2bf(acc[mi][ni][r] + bv_);
      } else {
        size_t base = ((size_t)((b * H_ + h) * HD_ + hd)) * S_ + sb;
        ushort4 o;
        o.x = f2bf(acc[mi][ni][0] + bv_);
        o.y = f2bf(acc[mi][ni][1] + bv_);
        o.z = f2bf(acc[mi][ni][2] + bv_);
        o.w = f2bf(acc[mi][ni][3] + bv_);
        *(ushort4*)&dst[base] = o;
      }
    }
  }
}

// ---------------------------------------------------------------------------
// Kernel 2 (v10): v9 LDS-staged flash attention with three trims:
//  - LDS exactly 32768 B (was 40960 w/ pad): v9's occupancy read 20.6% ~=
//    2 blocks/CU, consistent with LDS granule rounding 40KB up; 32KB exact
//    should restore 4 blocks/CU (grid residency).
//  - exp in exp2 domain: p = v_exp_f32(Cm*(0.125*log2e) + mb). Removes the
//    v_mul inside __expf (32/iter).
//  - l-sum on the matrix pipe: accl[s] = mfma(ones_A, pf[s], accl) — with
//    A=ones, D[m][q] = sum_k P[q][k] for every m, so accl holds l for this
//    lane's q-column. Removes 24 serial VALU adds/iter + epilogue shuffles;
//    adds 4 MFMA/iter on the 20%-busy matrix pipe.
// K/V LDS swizzle + P/V fragment mappings identical to v9 (verified).
// ---------------------------------------------------------------------------
__global__ __launch_bounds__(256)
void attn_kernel(
    const unsigned short* __restrict__ Q, const unsigned short* __restrict__ K,
    const unsigned short* __restrict__ Vt, const int* __restrict__ mask,
    unsigned short* __restrict__ ctx)
{
  __shared__ unsigned short Kl[2][4096];  // 8 KB per buffer
  __shared__ unsigned short Vl[2][4096];  // total 32768 B exactly

  const int wv   = threadIdx.x >> 6;
  const int lane = threadIdx.x & 63;
  const int c    = lane & 15;
  const int quad = lane >> 4;

  const int id = blockIdx.x;
  const int bh = (id & 7) + 8 * (id >> 7);   // bh%8 == id%8 (XCD co-location)
  const int qt = (id >> 3) & 15;
  const int b  = bh >> 4;
  const int h  = bh & 15;
  const int q0 = qt * 128 + wv * 32;         // 32 q-rows per wave

  const unsigned short* Qb = Q  + (size_t)bh * S_ * HD_;
  const unsigned short* Kb = K  + (size_t)bh * S_ * HD_;
  const unsigned short* Vb = Vt + (size_t)bh * HD_ * S_;
  const int* mrow = mask + b * S_;

  // Q as B-fragments (B-row j = q = lane&15)
  short8 bQ[2][2];
  #pragma unroll
  for (int s = 0; s < 2; ++s) {
    const unsigned short* qrow = Qb + (size_t)(q0 + s * 16 + c) * HD_;
    bQ[s][0] = *(const short8*)(qrow + quad * 8);
    bQ[s][1] = *(const short8*)(qrow + 32 + quad * 8);
  }

  short8 ones;
  #pragma unroll
  for (int i = 0; i < 8; ++i) ones[i] = (short)0x3F80;  // bf16 1.0

  floatx4 acc[2][4], accl[2];
  #pragma unroll
  for (int s = 0; s < 2; ++s) {
    #pragma unroll
    for (int d = 0; d < 4; ++d) acc[s][d] = (floatx4){0.f, 0.f, 0.f, 0.f};
    accl[s] = (floatx4){0.f, 0.f, 0.f, 0.f};
  }

  const float SC = 0.125f * 1.44269504089f;  // (1/sqrt(64)) * log2(e)

  // Stage one 64-k tile of K and V into LDS buffer `buf` (linear dest,
  // XOR-permuted global source realizes the swizzled layout).
  auto stageKV = [&](int buf, int kp0) {
    #pragma unroll
    for (int j = 0; j < 2; ++j) {
      const int Pb  = j * 256 + (wv << 6);
      const int P   = Pb + lane;
      const int row = P >> 3;
      const int c8  = (P & 7) ^ (row & 7);
      __builtin_amdgcn_global_load_lds(
          (glob_uint*)(Kb + (size_t)(kp0 + row) * HD_ + c8 * 8),
          (lds_uint*)&Kl[buf][Pb * 8], 16, 0, 0);
      __builtin_amdgcn_global_load_lds(
          (glob_uint*)(Vb + (size_t)row * S_ + kp0 + c8 * 8),
          (lds_uint*)&Vl[buf][Pb * 8], 16, 0, 0);
    }
  };

  stageKV(0, 0);
  __syncthreads();
  int cur = 0;

  for (int t = 0; t < S_ / 64; ++t) {
    const int kp0 = t * 64;
    if (t + 1 < S_ / 64) stageKV(cur ^ 1, kp0 + 64);

    // mask words for this tile (L2-resident; latency hides under QK^T)
    int4 mk4[4];
    #pragma unroll
    for (int ct = 0; ct < 4; ++ct)
      mk4[ct] = *(const int4*)(mrow + kp0 + ct * 16 + quad * 4);

    // ---- QK^T (swapped) from swizzled LDS K tile ----
    floatx4 Cm[2][4];
    #pragma unroll
    for (int kt2 = 0; kt2 < 4; ++kt2) {
      const int krow = kt2 * 16 + c;
      const int sw   = krow & 7;
      short8 k0 = *(const short8*)&Kl[cur][krow * 64 + ((quad) ^ sw) * 8];
      short8 k1 = *(const short8*)&Kl[cur][krow * 64 + ((4 + quad) ^ sw) * 8];
      floatx4 z0 = {0.f,0.f,0.f,0.f}, z1 = {0.f,0.f,0.f,0.f};
      z0 = __builtin_amdgcn_mfma_f32_16x16x32_bf16(k0, bQ[0][0], z0, 0, 0, 0);
      z1 = __builtin_amdgcn_mfma_f32_16x16x32_bf16(k0, bQ[1][0], z1, 0, 0, 0);
      z0 = __builtin_amdgcn_mfma_f32_16x16x32_bf16(k1, bQ[0][1], z0, 0, 0, 0);
      z1 = __builtin_amdgcn_mfma_f32_16x16x32_bf16(k1, bQ[1][1], z1, 0, 0, 0);
      Cm[0][kt2] = z0;
      Cm[1][kt2] = z1;
    }

    // ---- mask + exp2 (static max) + pack to bf16 pairs ----
    unsigned w[2][4][2];
    #pragma unroll
    for (int ct = 0; ct < 4; ++ct) {
      const float mb0 = (mk4[ct].x == 0) ? -1e30f : 0.f;
      const float mb1 = (mk4[ct].y == 0) ? -1e30f : 0.f;
      const float mb2 = (mk4[ct].z == 0) ? -1e30f : 0.f;
      const float mb3 = (mk4[ct].w == 0) ? -1e30f : 0.f;
      #pragma unroll
      for (int s = 0; s < 2; ++s) {
        float p0 = exp2_fast(fmaf(Cm[s][ct][0], SC, mb0));
        float p1 = exp2_fast(fmaf(Cm[s][ct][1], SC, mb1));
        float p2 = exp2_fast(fmaf(Cm[s][ct][2], SC, mb2));
        float p3 = exp2_fast(fmaf(Cm[s][ct][3], SC, mb3));
        w[s][ct][0] = cvtpk_bf16(p0, p1);
        w[s][ct][1] = cvtpk_bf16(p2, p3);
      }
    }

    // ---- PV + l-sum: P B-frags in-register; V A-frags from swizzled LDS ----
    #pragma unroll
    for (int ch = 0; ch < 2; ++ch) {
      short8 pf[2];
      #pragma unroll
      for (int s = 0; s < 2; ++s) {
        unsigned a0 = w[s][2 * ch][0],     a1 = w[s][2 * ch][1];
        unsigned b0 = w[s][2 * ch + 1][0], b1 = w[s][2 * ch + 1][1];
        PSWAP(a0, b0);
        PSWAP(a1, b1);
        uint4v pw = {a0, a1, b0, b1};
        pf[s] = __builtin_bit_cast(short8, pw);
      }
      const int c0 = ch * 4 + (quad >> 1) * 2;   // first 16B chunk of 8B pair
      const int h0 = (quad & 1) * 4;             // 8B half within chunk (ushorts)
      #pragma unroll
      for (int dt = 0; dt < 4; ++dt) {
        const int vrow = dt * 16 + c;
        const int sw   = vrow & 7;
        uint2 vlo = *(const uint2*)&Vl[cur][vrow * 64 + ((c0)     ^ sw) * 8 + h0];
        uint2 vhi = *(const uint2*)&Vl[cur][vrow * 64 + ((c0 + 1) ^ sw) * 8 + h0];
        uint4v vw = {vlo.x, vlo.y, vhi.x, vhi.y};
        short8 vf = __builtin_bit_cast(short8, vw);
        acc[0][dt] = __builtin_amdgcn_mfma_f32_16x16x32_bf16(vf, pf[0], acc[0][dt], 0, 0, 0);
        acc[1][dt] = __builtin_amdgcn_mfma_f32_16x16x32_bf16(vf, pf[1], acc[1][dt], 0, 0, 0);
      }
      accl[0] = __builtin_amdgcn_mfma_f32_16x16x32_bf16(ones, pf[0], accl[0], 0, 0, 0);
      accl[1] = __builtin_amdgcn_mfma_f32_16x16x32_bf16(ones, pf[1], accl[1], 0, 0, 0);
    }

    __syncthreads();
    cur ^= 1;
  }

  // ---- epilogue: accl already holds l (row-sum) for this lane's q-column --
  #pragma unroll
  for (int s = 0; s < 2; ++s) {
    const float inv = 1.f / accl[s][0];
    #pragma unroll
    for (int dt = 0; dt < 4; ++dt) {
      ushort4 o;
      o.x = f2bf(acc[s][dt][0] * inv);
      o.y = f2bf(acc[s][dt][1] * inv);
      o.z = f2bf(acc[s][dt][2] * inv);
      o.w = f2bf(acc[s][dt][3] * inv);
      *(ushort4*)&ctx[((size_t)(b * S_ + q0 + s * 16 + c)) * D_ +
                      h * HD_ + dt * 16 + quad * 4] = o;
    }
  }
}

// ---------------------------------------------------------------------------
// Kernel 3: out-proj + residual (tiled). y[m,n] = ctx@Wo.T + bo + x. y fp32.
// ---------------------------------------------------------------------------
__global__ __launch_bounds__(256) void gemm_out(
    const unsigned short* __restrict__ CTX, const unsigned short* __restrict__ W,
    const float* __restrict__ bo, const float* __restrict__ X,
    float* __restrict__ Y)
{
  GEMM_MAINLOOP(CTX, W)

  #pragma unroll
  for (int mi = 0; mi < 4; ++mi) {
    const int m = m0 + wr + mi * 16 + quad * 4;
    #pragma unroll
    for (int ni = 0; ni < 4; ++ni) {
      const int n = n0 + wc + ni * 16 + c;
      const float bias = bo[n];
      #pragma unroll
      for (int r = 0; r < 4; ++r)
        Y[(size_t)(m + r) * D_ + n] =
            acc[mi][ni][r] + bias + X[(size_t)(m + r) * D_ + n];
    }
  }
}

// ---------------------------------------------------------------------------
// Kernel 4: LayerNorm over last dim (1024). y fp32 in; OUTPUT FP32.
// ---------------------------------------------------------------------------
__global__ __launch_bounds__(256) void ln_kernel(
    const float* __restrict__ Y, const float* __restrict__ gamma,
    const float* __restrict__ beta, float* __restrict__ out)
{
  __shared__ float red[2][4];
  const int row  = blockIdx.x;
  const int tid  = threadIdx.x;
  const int wv   = tid >> 6;
  const int lane = tid & 63;
  const float* y = Y + (size_t)row * D_;

  float v[4];
  float sum = 0.f, sumsq = 0.f;
  #pragma unroll
  for (int i = 0; i < 4; ++i) {
    v[i] = y[tid + i * 256];
    sum += v[i];
    sumsq += v[i] * v[i];
  }
  #pragma unroll
  for (int off = 32; off > 0; off >>= 1) {
    sum   += __shfl_down(sum, off, 64);
    sumsq += __shfl_down(sumsq, off, 64);
  }
  if (lane == 0) { red[0][wv] = sum; red[1][wv] = sumsq; }
  __syncthreads();
  sum   = red[0][0] + red[0][1] + red[0][2] + red[0][3];
  sumsq = red[1][0] + red[1][1] + red[1][2] + red[1][3];

  const float mu   = sum * (1.f / D_);
  const float var  = sumsq * (1.f / D_) - mu * mu;
  const float rstd = rsqrtf(var + 1e-5f);

  #pragma unroll
  for (int i = 0; i < 4; ++i) {
    const int col = tid + i * 256;
    out[(size_t)row * D_ + col] = (v[i] - mu) * rstd * gamma[col] + beta[col];
  }
}

// ---------------------------------------------------------------------------
extern "C" void kernel_launch(void* const* d_in, const int* in_sizes, int n_in,
                              void* d_out, int out_size, void* d_ws, size_t ws_size,
                              hipStream_t stream) {
  const float* x     = (const float*)d_in[0];
  const int*   mask  = (const int*)d_in[1];
  const float* Wq    = (const float*)d_in[2];
  const float* bq    = (const float*)d_in[3];
  const float* Wk    = (const float*)d_in[4];
  const float* bk    = (const float*)d_in[5];
  const float* Wv    = (const float*)d_in[6];
  const float* bv    = (const float*)d_in[7];
  const float* Wo    = (const float*)d_in[8];
  const float* bo    = (const float*)d_in[9];
  const float* gamma = (const float*)d_in[10];
  const float* beta  = (const float*)d_in[11];

  char* ws = (char*)d_ws;
  unsigned short* xb    = (unsigned short*)(ws + WS_XB);
  unsigned short* wqb   = (unsigned short*)(ws + WS_WQ);
  unsigned short* wkb   = (unsigned short*)(ws + WS_WK);
  unsigned short* wvb   = (unsigned short*)(ws + WS_WV);
  unsigned short* wob   = (unsigned short*)(ws + WS_WO);
  unsigned short* q_ws  = (unsigned short*)(ws + WS_Q);
  unsigned short* k_ws  = (unsigned short*)(ws + WS_KK);
  unsigned short* vt_ws = (unsigned short*)(ws + WS_VT);
  float*          y_ws  = (float*)(ws + WS_Y);
  unsigned short* ctx   = (unsigned short*)d_out;

  const int nx4 = (BS_ * D_) / 4;
  const int nw4 = (D_ * D_) / 4;
  cvt_f32_bf16<<<(nx4 + 255) / 256, 256, 0, stream>>>(x,  xb,  nx4);
  cvt_f32_bf16<<<(nw4 + 255) / 256, 256, 0, stream>>>(Wq, wqb, nw4);
  cvt_f32_bf16<<<(nw4 + 255) / 256, 256, 0, stream>>>(Wk, wkb, nw4);
  cvt_f32_bf16<<<(nw4 + 255) / 256, 256, 0, stream>>>(Wv, wvb, nw4);
  cvt_f32_bf16<<<(nw4 + 255) / 256, 256, 0, stream>>>(Wo, wob, nw4);

  gemm_qkv<<<dim3(BS_ / BM, D_ / BN, 3), 256, 0, stream>>>(
      xb, wqb, bq, wkb, bk, wvb, bv, q_ws, k_ws, vt_ws);

  attn_kernel<<<dim3(16 * 64), 256, 0, stream>>>(   // 1024 blocks, swizzled
      q_ws, k_ws, vt_ws, mask, ctx);

  gemm_out<<<dim3(BS_ / BM, D_ / BN), 256, 0, stream>>>(
      ctx, wob, bo, x, y_ws);

  ln_kernel<<<BS_, 256, 0, stream>>>(y_ws, gamma, beta, (float*)d_out);
}